// Round 1
// baseline (9192.107 us; speedup 1.0000x reference)
//
#include <hip/hip_runtime.h>

// Semi-CRF log-partition, relay-pipeline design.
// B=4, T=512, L=96, W=63 (K=64).
//
// Math: alpha[t,ln] = LSE_{s,lp}( alpha[s,lp] + w(s,t)*(seg[b,s+1,t,ln]+trans[lp,ln]) ) (+) z(t,ln)
//   w(s,t) = s+1-max(0,t-W).  For fixed d=t-s: w = 64-d for t>W, and ramps 1,2,... for t<=W.
// Factor over lp:  contribution_d[ln] = C[s] + w*seg + log( sum_lp Aexp[s,lp] * E[lp,ln]^w ),
//   Aexp[s,lp] = exp(alpha[s,lp]-C[s]), C[s]=max_lp alpha[s,lp], E = exp(trans).
// Block (b,d) keeps R = E^w column-sliced in registers (96 VGPR/thread); one elementwise
// multiply per ramp step keeps it current. Relay: running (m, v) accumulator for each target t
// passes from block d+1 to block d (stamp flag); block d=1 finalizes + publishes Aexp (pub flag).
// 252 blocks x 128 threads, ~37KB LDS -> trivially all co-resident on 256 CUs.

#define Tn 512
#define Ln 96
#define Wn 63
#define ND 63
#define NEGINF (-1e30f)

#define SIDX(b, i, t) ((((size_t)(b) * Tn + (i)) * Tn + (t)) * Ln)

__device__ __forceinline__ float wmaxred(float v) {
#pragma unroll
  for (int m = 32; m >= 1; m >>= 1) v = fmaxf(v, __shfl_xor(v, m, 64));
  return v;
}
__device__ __forceinline__ float wsumred(float v) {
#pragma unroll
  for (int m = 32; m >= 1; m >>= 1) v += __shfl_xor(v, m, 64);
  return v;
}
__device__ __forceinline__ unsigned long long pack2(float a, float b) {
  return (unsigned long long)__float_as_uint(a) |
         ((unsigned long long)__float_as_uint(b) << 32);
}

__global__ void init_flags(int* stamp, int* pub) {
  int i = blockIdx.x * blockDim.x + threadIdx.x;
  if (i < 4 * Tn) stamp[i] = 0;
  if (i < 4) pub[i] = -1;
}

__global__ __launch_bounds__(128) void semicrf_relay(
    const float* __restrict__ seg, const float* __restrict__ tr,
    float* __restrict__ out, float* aex, float* Cb,
    unsigned long long* acc, int* stamp, int* pub) {
  const int blk = blockIdx.x;
  const int b = blk / ND;
  const int d = (blk % ND) + 1;  // offset this block owns, 1..63
  const int tid = threadIdx.x;
  const bool act = tid < Ln;
  const int ln = act ? tid : (Ln - 1);  // cap so inactive lanes read valid slots

  __shared__ float E[Ln * Ln];   // exp(trans), 36KB
  __shared__ float Albuf[Ln];    // Aexp[s] staging
  __shared__ float sred[2];

  for (int i = tid; i < Ln * Ln; i += 128) E[i] = __expf(tr[i]);
  __syncthreads();

  // R[lp] = E[lp][ln]^w, starts at w=1
  float R[Ln];
#pragma unroll
  for (int lp = 0; lp < Ln; ++lp) R[lp] = E[lp * Ln + ln];

  const float bos = tr[Ln * Ln + ln];

  if (d == 1) {
    // seed alpha[0] = exp(seg[b,0,0,:] + bos)   (reference stores the exp'd value)
    float a0 = __expf(seg[SIDX(b, 0, 0) + ln] + bos);
    float wm = wmaxred(act ? a0 : NEGINF);
    if ((tid & 63) == 0) sred[tid >> 6] = wm;
    __syncthreads();
    float C0 = fmaxf(sred[0], sred[1]);
    if (act)
      __hip_atomic_store(&aex[(b * Tn + 0) * Ln + tid], __expf(a0 - C0),
                         __ATOMIC_RELAXED, __HIP_MEMORY_SCOPE_AGENT);
    if (tid == 0)
      __hip_atomic_store(&Cb[b * Tn + 0], C0, __ATOMIC_RELAXED,
                         __HIP_MEMORY_SCOPE_AGENT);
    __threadfence();
    __syncthreads();
    if (tid == 0)
      __hip_atomic_store(&pub[b], 0, __ATOMIC_RELEASE, __HIP_MEMORY_SCOPE_AGENT);
  }

  int wcur = 1;
  for (int t = d; t < Tn; ++t) {
    const int s = t - d;
    const int w = (t <= Wn) ? (t - d + 1) : (64 - d);
    if (w > wcur) {  // ramp: w increments by exactly 1 per step while t<=W
#pragma unroll
      for (int lp = 0; lp < Ln; ++lp) R[lp] *= E[lp * Ln + ln];
      wcur = w;
    }

    // Issue independent global loads early (latency hides under the spin).
    const float segv = seg[SIDX(b, s + 1, t) + ln];
    float zv = NEGINF;
    if (d == 1 && t <= Wn)
      zv = (float)(t + 1) * (seg[SIDX(b, 0, t) + ln] + bos);

    // wait for alpha[s] to be published
    while (__hip_atomic_load(&pub[b], __ATOMIC_ACQUIRE,
                             __HIP_MEMORY_SCOPE_AGENT) < s)
      __builtin_amdgcn_s_sleep(1);
    __syncthreads();  // also protects Albuf reuse from previous iteration
    if (act)
      Albuf[tid] = __hip_atomic_load(&aex[(b * Tn + s) * Ln + tid],
                                     __ATOMIC_RELAXED, __HIP_MEMORY_SCOPE_AGENT);
    const float Cs = __hip_atomic_load(&Cb[b * Tn + s], __ATOMIC_RELAXED,
                                       __HIP_MEMORY_SCOPE_AGENT);
    __syncthreads();

    const int tIdx = b * Tn + t;
    const bool initAcc = (d == ND) || (s == 0);  // first contributor for target t
    float pm = 0.f, pv = 0.f;
    if (!initAcc) {
      // wait for block d+1's merge of target t, then pull the running (m,v)
      while (__hip_atomic_load(&stamp[tIdx], __ATOMIC_ACQUIRE,
                               __HIP_MEMORY_SCOPE_AGENT) != d + 1)
        __builtin_amdgcn_s_sleep(1);
      unsigned long long u =
          __hip_atomic_load(&acc[(size_t)tIdx * Ln + ln], __ATOMIC_RELAXED,
                            __HIP_MEMORY_SCOPE_AGENT);
      pm = __uint_as_float((unsigned)(u & 0xffffffffULL));
      pv = __uint_as_float((unsigned)(u >> 32));
    }

    // inner[ln] = sum_lp Aexp[s,lp] * E[lp,ln]^w   (Albuf broadcast, R in VGPRs)
    float i0 = 0.f, i1 = 0.f, i2 = 0.f, i3 = 0.f;
#pragma unroll
    for (int lp = 0; lp < Ln; lp += 4) {
      i0 = fmaf(Albuf[lp + 0], R[lp + 0], i0);
      i1 = fmaf(Albuf[lp + 1], R[lp + 1], i1);
      i2 = fmaf(Albuf[lp + 2], R[lp + 2], i2);
      i3 = fmaf(Albuf[lp + 3], R[lp + 3], i3);
    }
    const float inner = (i0 + i1) + (i2 + i3);  // in [1, 2.2e29]: safe fp32
    const float c = Cs + (float)w * segv + __logf(inner);

    float m, v;
    if (initAcc) {
      m = c;
      v = 1.0f;
    } else {
      const float nm = fmaxf(pm, c);
      v = pv * __expf(pm - nm) + __expf(c - nm);
      m = nm;
    }

    if (d > 1) {
      if (act)
        __hip_atomic_store(&acc[(size_t)tIdx * Ln + tid], pack2(m, v),
                           __ATOMIC_RELAXED, __HIP_MEMORY_SCOPE_AGENT);
      __threadfence();
      __syncthreads();
      if (tid == 0)
        __hip_atomic_store(&stamp[tIdx], d, __ATOMIC_RELEASE,
                           __HIP_MEMORY_SCOPE_AGENT);
    } else {
      // finalize alpha[t]: merge z-term (t<=W), LSE, publish scaled-exp form
      if (t <= Wn) {
        const float nm = fmaxf(m, zv);
        v = v * __expf(m - nm) + __expf(zv - nm);
        m = nm;
      }
      const float alpha = m + __logf(v);
      float wm = wmaxred(act ? alpha : NEGINF);
      if ((tid & 63) == 0) sred[tid >> 6] = wm;
      __syncthreads();
      const float C = fmaxf(sred[0], sred[1]);
      __syncthreads();
      const float ax = __expf(alpha - C);
      if (act)
        __hip_atomic_store(&aex[tIdx * Ln + tid], ax, __ATOMIC_RELAXED,
                           __HIP_MEMORY_SCOPE_AGENT);
      if (tid == 0)
        __hip_atomic_store(&Cb[tIdx], C, __ATOMIC_RELAXED,
                           __HIP_MEMORY_SCOPE_AGENT);
      __threadfence();
      __syncthreads();
      if (tid == 0)
        __hip_atomic_store(&pub[b], t, __ATOMIC_RELEASE,
                           __HIP_MEMORY_SCOPE_AGENT);
      if (t == Tn - 1) {
        float sm = wsumred(act ? ax : 0.f);
        if ((tid & 63) == 0) sred[tid >> 6] = sm;
        __syncthreads();
        if (tid == 0) out[b] = C + __logf(sred[0] + sred[1]);
      }
    }
  }
}

extern "C" void kernel_launch(void* const* d_in, const int* in_sizes, int n_in,
                              void* d_out, int out_size, void* d_ws,
                              size_t ws_size, hipStream_t stream) {
  const float* seg = (const float*)d_in[0];  // (4,512,512,96) f32
  const float* tr = (const float*)d_in[1];   // (97,96) f32
  float* out = (float*)d_out;                // (4,) f32

  // workspace layout (~2.4 MB)
  float* aex = (float*)d_ws;                                   // 4*512*96
  float* Cb = aex + (size_t)4 * Tn * Ln;                       // 4*512
  unsigned long long* acc = (unsigned long long*)(Cb + 4 * Tn);// 4*512*96 (m,v)
  int* stamp = (int*)(acc + (size_t)4 * Tn * Ln);              // 4*512
  int* pub = stamp + 4 * Tn;                                   // 4

  hipLaunchKernelGGL(init_flags, dim3(9), dim3(256), 0, stream, stamp, pub);
  hipLaunchKernelGGL(semicrf_relay, dim3(4 * ND), dim3(128), 0, stream, seg, tr,
                     out, aex, Cb, acc, stamp, pub);
}

// Round 2
// 1180.545 us; speedup vs baseline: 7.7863x; 7.7863x over previous
//
#include <hip/hip_runtime.h>

// Semi-CRF log-partition. B=4, T=512, L=96, W=63.
// Relay pipeline with self-validating 8B relaxed-atomic handoffs:
//   axp[(b,s,ln)] = pack(ax=exp(alpha[s,ln]-C[s]), C[s])  (NaN sentinel in C word)
//   acc[(b,t,ln)] = pack(m, v|tag)  running LSE accumulator, tag = writer offset d
// Finalizer block per batch owns d=1,2 locally (R=E^w in VGPRs, alpha in LDS);
// relay blocks own d=3..63. No fences anywhere: each handoff is one 8B atomic.

#define Tn 512
#define Ln 96
#define Wn 63
#define ND 63
#define NBLK 62  // 1 finalizer + 61 relay (d=3..63) per batch
#define NEGINF (-1e30f)
#define SIDX(b, i, t) ((((size_t)(b) * Tn + (i)) * Tn + (t)) * Ln)
#define AGENT __HIP_MEMORY_SCOPE_AGENT
#define RLX __ATOMIC_RELAXED

__device__ __forceinline__ float wmaxred(float v) {
#pragma unroll
  for (int m = 32; m >= 1; m >>= 1) v = fmaxf(v, __shfl_xor(v, m, 64));
  return v;
}
__device__ __forceinline__ float wsumred(float v) {
#pragma unroll
  for (int m = 32; m >= 1; m >>= 1) v += __shfl_xor(v, m, 64);
  return v;
}
__device__ __forceinline__ unsigned long long pack2(float lo, float hi) {
  return (unsigned long long)__float_as_uint(lo) |
         ((unsigned long long)__float_as_uint(hi) << 32);
}

__global__ void init_ws(unsigned long long* axp, unsigned long long* acc) {
  size_t i = (size_t)blockIdx.x * 256 + threadIdx.x;
  if (i < (size_t)4 * Tn * Ln) {
    axp[i] = 0x7FC00000ULL << 32;  // hi word = NaN sentinel
    acc[i] = 0ULL;                 // tag 0 = empty
  }
}

__global__ __launch_bounds__(128, 1) void semicrf(
    const float* __restrict__ seg, const float* __restrict__ tr,
    float* __restrict__ out, unsigned long long* axp,
    unsigned long long* acc) {
  const int blk = blockIdx.x;
  const int b = blk / NBLK;
  const int role = blk % NBLK;  // 0 = finalizer, else offset d = role+2
  const int tid = threadIdx.x;
  const bool act = tid < Ln;
  const int ln = act ? tid : (Ln - 1);

  __shared__ float E[Ln * Ln];  // exp(trans), 36KB
  __shared__ float Alb[2][Ln];
  __shared__ float sred[2];

  for (int i = tid; i < Ln * Ln; i += 128) E[i] = __expf(tr[i]);
  const float bos = tr[Ln * Ln + ln];
  __syncthreads();

  if (role == 0) {
    // ================= finalizer: d=1,2 local + z + tag-3 merge =============
    float R1[Ln], R2[Ln];
#pragma unroll
    for (int lp = 0; lp < Ln; ++lp) {
      R1[lp] = E[lp * Ln + ln];
      R2[lp] = R1[lp];
    }
    int w1c = 1, w2c = 1;

    // seed alpha[0] = exp(seg[b,0,0,:] + bos)
    float a0 = __expf(seg[SIDX(b, 0, 0) + ln] + bos);
    float wm = wmaxred(act ? a0 : NEGINF);
    if ((tid & 63) == 0) sred[tid >> 6] = wm;
    __syncthreads();
    float Cs = fmaxf(sred[0], sred[1]);  // C for s
    float Cp = Cs;                       // C for s-1
    __syncthreads();
    const float ax0 = __expf(a0 - Cs);
    if (act) {
      Alb[0][tid] = ax0;
      __hip_atomic_store(&axp[((size_t)b * Tn + 0) * Ln + tid], pack2(ax0, Cs),
                         RLX, AGENT);
    }
    __syncthreads();

    for (int t = 1; t < Tn; ++t) {
      const int s = t - 1;
      // early loads (hide MALL/HBM latency under the matvecs)
      const size_t aIdx = ((size_t)b * Tn + t) * Ln + ln;
      unsigned long long u = 0;
      if (t >= 3) u = __hip_atomic_load(&acc[aIdx], RLX, AGENT);
      const float s1 = seg[SIDX(b, t, t) + ln];
      const float s2 = (t >= 2) ? seg[SIDX(b, t - 1, t) + ln] : 0.f;
      const float sz = (t <= Wn) ? seg[SIDX(b, 0, t) + ln] : 0.f;

      const int w1 = (t <= Wn) ? t : 63;
      if (w1 > w1c) {
        w1c = w1;
#pragma unroll
        for (int lp = 0; lp < Ln; ++lp) R1[lp] *= E[lp * Ln + ln];
      }
      int w2 = 0;
      if (t >= 2) {
        w2 = (t - 1 <= 62) ? (t - 1) : 62;
        if (w2 > w2c) {
          w2c = w2;
#pragma unroll
          for (int lp = 0; lp < Ln; ++lp) R2[lp] *= E[lp * Ln + ln];
        }
      }

      float i0 = 0, i1 = 0, i2 = 0, i3 = 0;
#pragma unroll
      for (int lp = 0; lp < Ln; lp += 4) {
        i0 = fmaf(Alb[s & 1][lp + 0], R1[lp + 0], i0);
        i1 = fmaf(Alb[s & 1][lp + 1], R1[lp + 1], i1);
        i2 = fmaf(Alb[s & 1][lp + 2], R1[lp + 2], i2);
        i3 = fmaf(Alb[s & 1][lp + 3], R1[lp + 3], i3);
      }
      const float c1 = Cs + (float)w1 * s1 + __logf((i0 + i1) + (i2 + i3));
      float m = c1, v = 1.f;
      if (t >= 2) {
        float j0 = 0, j1 = 0, j2 = 0, j3 = 0;
#pragma unroll
        for (int lp = 0; lp < Ln; lp += 4) {
          j0 = fmaf(Alb[(s - 1) & 1][lp + 0], R2[lp + 0], j0);
          j1 = fmaf(Alb[(s - 1) & 1][lp + 1], R2[lp + 1], j1);
          j2 = fmaf(Alb[(s - 1) & 1][lp + 2], R2[lp + 2], j2);
          j3 = fmaf(Alb[(s - 1) & 1][lp + 3], R2[lp + 3], j3);
        }
        const float c2 = Cp + (float)w2 * s2 + __logf((j0 + j1) + (j2 + j3));
        const float nm = fmaxf(m, c2);
        v = v * __expf(m - nm) + __expf(c2 - nm);
        m = nm;
      }
      if (t >= 3) {  // merge relayed accumulator (tag 3, 2 steps of slack)
        while (((u >> 32) & 0xFFu) != 3u) {
          __builtin_amdgcn_s_sleep(1);
          u = __hip_atomic_load(&acc[aIdx], RLX, AGENT);
        }
        const float pm = __uint_as_float((unsigned)u);
        const float pv = __uint_as_float(((unsigned)(u >> 32)) & ~0xFFu);
        const float nm = fmaxf(m, pm);
        v = v * __expf(m - nm) + pv * __expf(pm - nm);
        m = nm;
      }
      if (t <= Wn) {  // z-term
        const float zv = (float)(t + 1) * (sz + bos);
        const float nm = fmaxf(m, zv);
        v = v * __expf(m - nm) + __expf(zv - nm);
        m = nm;
      }
      const float alpha = m + __logf(v);
      float wmx = wmaxred(act ? alpha : NEGINF);
      if ((tid & 63) == 0) sred[tid >> 6] = wmx;
      __syncthreads();
      const float C = fmaxf(sred[0], sred[1]);
      __syncthreads();  // Alb write-after-read + sred reuse
      const float axn = __expf(alpha - C);
      if (act) {
        Alb[t & 1][tid] = axn;
        __hip_atomic_store(&axp[((size_t)b * Tn + t) * Ln + tid],
                           pack2(axn, C), RLX, AGENT);
      }
      Cp = Cs;
      Cs = C;
      __syncthreads();  // Alb visible to next iteration
      if (t == Tn - 1) {
        float sm = wsumred(act ? axn : 0.f);
        if ((tid & 63) == 0) sred[tid >> 6] = sm;
        __syncthreads();
        if (tid == 0) out[b] = C + __logf(sred[0] + sred[1]);
      }
    }
  } else {
    // ================= relay block, offset d = role+2 in [3..63] ============
    const int d = role + 2;
    float R[Ln];
#pragma unroll
    for (int lp = 0; lp < Ln; ++lp) R[lp] = E[lp * Ln + ln];
    int wc = 1;

    for (int t = d; t < Tn; ++t) {
      const int s = t - d;
      const int w = (t <= Wn) ? (t - d + 1) : (64 - d);
      if (w > wc) {
        wc = w;
#pragma unroll
        for (int lp = 0; lp < Ln; ++lp) R[lp] *= E[lp * Ln + ln];
      }
      const float segv = seg[SIDX(b, s + 1, t) + ln];
      const size_t tIdx = ((size_t)b * Tn + t) * Ln + ln;
      const bool initAcc = (d == ND) || (s == 0);
      unsigned long long ua = 0;
      if (!initAcc) ua = __hip_atomic_load(&acc[tIdx], RLX, AGENT);  // early

      // poll alpha[s] (self-validating: NaN sentinel in C word)
      const size_t pIdx = ((size_t)b * Tn + s) * Ln + ln;
      unsigned long long up = __hip_atomic_load(&axp[pIdx], RLX, AGENT);
      while (((unsigned)(up >> 32)) == 0x7FC00000u) {
        __builtin_amdgcn_s_sleep(1);
        up = __hip_atomic_load(&axp[pIdx], RLX, AGENT);
      }
      __syncthreads();  // protect Alb[0] write-after-read
      if (act) Alb[0][tid] = __uint_as_float((unsigned)up);
      const float Cs = __uint_as_float((unsigned)(up >> 32));
      __syncthreads();

      float i0 = 0, i1 = 0, i2 = 0, i3 = 0;
#pragma unroll
      for (int lp = 0; lp < Ln; lp += 4) {
        i0 = fmaf(Alb[0][lp + 0], R[lp + 0], i0);
        i1 = fmaf(Alb[0][lp + 1], R[lp + 1], i1);
        i2 = fmaf(Alb[0][lp + 2], R[lp + 2], i2);
        i3 = fmaf(Alb[0][lp + 3], R[lp + 3], i3);
      }
      const float c = Cs + (float)w * segv + __logf((i0 + i1) + (i2 + i3));
      float m, v;
      if (initAcc) {
        m = c;
        v = 1.f;
      } else {
        while (((ua >> 32) & 0xFFu) != (unsigned)(d + 1)) {
          __builtin_amdgcn_s_sleep(1);
          ua = __hip_atomic_load(&acc[tIdx], RLX, AGENT);
        }
        const float pm = __uint_as_float((unsigned)ua);
        const float pv = __uint_as_float(((unsigned)(ua >> 32)) & ~0xFFu);
        const float nm = fmaxf(pm, c);
        v = pv * __expf(pm - nm) + __expf(c - nm);
        m = nm;
      }
      if (act) {
        const unsigned vb = (__float_as_uint(v) & ~0xFFu) | (unsigned)d;
        __hip_atomic_store(
            &acc[tIdx],
            (unsigned long long)__float_as_uint(m) |
                ((unsigned long long)vb << 32),
            RLX, AGENT);
      }
    }
  }
}

extern "C" void kernel_launch(void* const* d_in, const int* in_sizes, int n_in,
                              void* d_out, int out_size, void* d_ws,
                              size_t ws_size, hipStream_t stream) {
  const float* seg = (const float*)d_in[0];  // (4,512,512,96) f32
  const float* tr = (const float*)d_in[1];   // (97,96) f32
  float* out = (float*)d_out;                // (4,) f32

  unsigned long long* axp = (unsigned long long*)d_ws;      // 4*512*96 u64
  unsigned long long* acc = axp + (size_t)4 * Tn * Ln;      // 4*512*96 u64

  hipLaunchKernelGGL(init_ws, dim3(768), dim3(256), 0, stream, axp, acc);
  hipLaunchKernelGGL(semicrf, dim3(4 * NBLK), dim3(128), 0, stream, seg, tr,
                     out, axp, acc);
}

// Round 3
// 1037.464 us; speedup vs baseline: 8.8602x; 1.1379x over previous
//
#include <hip/hip_runtime.h>

// Semi-CRF log-partition. B=4, T=512, L=96, W=63.
// Topology v3: finalizer block (4 wave-pairs: d=1+core, d=2, d=3, d=4 via LDS)
// + relay pairs for d=5..63 organized as K=8 interleaved chains (d = j mod 8).
// Interior chain hops have 8 steps of slack; finalizer merges the 8 chain ends
// (d=5..12). Critical cycle: r >= (2V + W + F)/5 instead of /3 with depth-61.
// All handoffs are single 8B relaxed agent atomics (self-validating tag/sentinel).
// No __syncthreads after E-init; pair/wave sync via LDS acquire/release flags.

#define Tn 512
#define Ln 96
#define LSQ (Ln * Ln)
#define Wn 63
#define KCH 8
#define DMIN 5
#define RPB 4    // relay pairs (offsets) per block
#define NRB 15   // relay blocks per batch
#define BPB 16   // blocks per batch (1 finalizer + NRB)
#define NEGINF (-1e30f)
#define SENT 0x7FC00000u

#define AGENT __HIP_MEMORY_SCOPE_AGENT
#define WG __HIP_MEMORY_SCOPE_WORKGROUP
#define RLX __ATOMIC_RELAXED
#define ACQ __ATOMIC_ACQUIRE
#define REL __ATOMIC_RELEASE

#define SIDX(b, i, t) ((((size_t)(b) * Tn + (i)) * Tn + (t)) * Ln)

typedef unsigned long long u64;
typedef unsigned int u32;

__device__ __forceinline__ float wmaxred(float v) {
#pragma unroll
  for (int m = 32; m >= 1; m >>= 1) v = fmaxf(v, __shfl_xor(v, m, 64));
  return v;
}
__device__ __forceinline__ float wsumred(float v) {
#pragma unroll
  for (int m = 32; m >= 1; m >>= 1) v += __shfl_xor(v, m, 64);
  return v;
}
__device__ __forceinline__ u64 pack2(float lo, float hi) {
  return (u64)__float_as_uint(lo) | ((u64)__float_as_uint(hi) << 32);
}

__global__ void init_ws(u64* ws) {
  const size_t n = (size_t)4 * Tn * Ln * (1 + KCH);
  const size_t n1 = (size_t)4 * Tn * Ln;
  for (size_t i = (size_t)blockIdx.x * blockDim.x + threadIdx.x; i < n;
       i += (size_t)gridDim.x * blockDim.x)
    ws[i] = (i < n1) ? (((u64)SENT) << 32) : 0ull;
}

__global__ __launch_bounds__(512, 1) void semicrf(
    const float* __restrict__ seg, const float* __restrict__ tr,
    float* __restrict__ out, u64* axp, u64* acc) {
  const int b = blockIdx.x / BPB;
  const int role = blockIdx.x % BPB;
  const int tid = threadIdx.x;
  const int pair = tid >> 7;
  const int tp = tid & 127;
  const int wv = tp >> 6;
  const bool act = tp < Ln;
  const int ln = act ? tp : (Ln - 1);

  __shared__ __align__(16) float E[LSQ];        // exp(trans) 36 KB
  __shared__ __align__(16) float AlbR[8][Ln];   // finalizer alpha ring
  __shared__ float CRng[8];                     // finalizer C ring
  __shared__ float slotC[4][3][Ln];             // in-block pair contributions
  __shared__ __align__(16) float Alb_s[RPB][2][Ln];  // relay staging (dbuf)
  __shared__ float redbuf[2][2];                // [t&1][wv]
  __shared__ int seqAw[2];                      // alpha ring publish per wave
  __shared__ int sp[3][2];                      // slotC publish per pair/wave
  __shared__ int stg[RPB][2];                   // relay staging flags
  __shared__ int rfl[2];                        // pair0 reduction flags

  if (tid < 2) { seqAw[tid] = -1; rfl[tid] = -1; }
  if (tid < 6) sp[tid >> 1][tid & 1] = -1;
  if (tid < RPB * 2) stg[tid >> 1][tid & 1] = -1;
  for (int i = tid; i < LSQ; i += 512) E[i] = __expf(tr[i]);
  __syncthreads();  // the ONLY block-wide barrier

  if (role != 0) {
    // ===================== relay pair, offset d in [5..63] ==================
    const int d = DMIN + RPB * (role - 1) + pair;
    if (d > Wn) return;  // role 15 pair 3 (d=64)
    const int j = d & 7;
    u64* chain = acc + (size_t)j * 4 * Tn * Ln;
    float R[Ln];
#pragma unroll
    for (int lp = 0; lp < Ln; ++lp) R[lp] = E[lp * Ln + ln];
    int wc = 1;
    const bool alwaysHead = (d + KCH > Wn);

    for (int t = d; t < Tn; ++t) {
      const int s = t - d;
      const int w = (t <= Wn) ? (s + 1) : (64 - d);
      if (w > wc) {
        wc = w;
#pragma unroll
        for (int lp = 0; lp < Ln; ++lp) R[lp] *= E[lp * Ln + ln];
      }
      const size_t tIdx = ((size_t)b * Tn + t) * Ln + ln;
      const bool head = alwaysHead || (s < KCH);
      u64 ua = 0;
      if (!head) ua = __hip_atomic_load(&chain[tIdx], RLX, AGENT);  // early
      const float segv = seg[SIDX(b, s + 1, t) + ln];

      // gate: alpha[s] (self-validating sentinel)
      const size_t pIdx = ((size_t)b * Tn + s) * Ln + ln;
      u64 up = __hip_atomic_load(&axp[pIdx], RLX, AGENT);
      while ((u32)(up >> 32) == SENT)
        up = __hip_atomic_load(&axp[pIdx], RLX, AGENT);

      // pair staging (double-buffered, per-wave flags)
      const int buf = t & 1;
      if (act) Alb_s[pair][buf][tp] = __uint_as_float((u32)up);
      const float Cs = __uint_as_float((u32)(up >> 32));
      __hip_atomic_store(&stg[pair][wv], t, REL, WG);
      while (__hip_atomic_load(&stg[pair][wv ^ 1], ACQ, WG) < t) {}

      float i0 = 0, i1 = 0, i2 = 0, i3 = 0;
      const float4* A4 = (const float4*)Alb_s[pair][buf];
#pragma unroll
      for (int q = 0; q < 24; ++q) {
        float4 a = A4[q];
        i0 = fmaf(a.x, R[4 * q + 0], i0);
        i1 = fmaf(a.y, R[4 * q + 1], i1);
        i2 = fmaf(a.z, R[4 * q + 2], i2);
        i3 = fmaf(a.w, R[4 * q + 3], i3);
      }
      const float c = Cs + (float)w * segv + __logf((i0 + i1) + (i2 + i3));

      float m, v;
      if (head) {
        m = c;
        v = 1.f;
      } else {
        while (((ua >> 32) & 0xFFu) != (u32)(d + KCH))
          ua = __hip_atomic_load(&chain[tIdx], RLX, AGENT);
        const float pm = __uint_as_float((u32)ua);
        const float pv = __uint_as_float(((u32)(ua >> 32)) & ~0xFFu);
        const float nm = fmaxf(pm, c);
        v = pv * __expf(pm - nm) + __expf(c - nm);
        m = nm;
      }
      if (act) {
        const u32 vb = (__float_as_uint(v) & ~0xFFu) | (u32)d;
        __hip_atomic_store(&chain[tIdx],
                           (u64)__float_as_uint(m) | ((u64)vb << 32), RLX,
                           AGENT);
      }
    }
    return;
  }

  // ======================= finalizer block ==================================
  if (pair != 0) {
    // ---- in-block pair: offset d = pair+1 in {2,3,4}, LDS-coupled ----------
    const int d = pair + 1;
    float R[Ln];
#pragma unroll
    for (int lp = 0; lp < Ln; ++lp) R[lp] = E[lp * Ln + ln];
    int wc = 1;
    for (int t = d; t < Tn; ++t) {
      const int s = t - d;
      const int w = (t <= Wn) ? (s + 1) : (64 - d);
      if (w > wc) {
        wc = w;
#pragma unroll
        for (int lp = 0; lp < Ln; ++lp) R[lp] *= E[lp * Ln + ln];
      }
      const float segv = seg[SIDX(b, s + 1, t) + ln];  // issue early
      while (__hip_atomic_load(&seqAw[0], ACQ, WG) < s) {}
      while (__hip_atomic_load(&seqAw[1], ACQ, WG) < s) {}
      const float Cs = CRng[s & 7];
      float i0 = 0, i1 = 0, i2 = 0, i3 = 0;
      const float4* A4 = (const float4*)AlbR[s & 7];
#pragma unroll
      for (int q = 0; q < 24; ++q) {
        float4 a = A4[q];
        i0 = fmaf(a.x, R[4 * q + 0], i0);
        i1 = fmaf(a.y, R[4 * q + 1], i1);
        i2 = fmaf(a.z, R[4 * q + 2], i2);
        i3 = fmaf(a.w, R[4 * q + 3], i3);
      }
      const float c = Cs + (float)w * segv + __logf((i0 + i1) + (i2 + i3));
      if (act) slotC[t & 3][pair - 1][tp] = c;
      __hip_atomic_store(&sp[pair - 1][wv], t, REL, WG);
    }
    return;
  }

  // ---- pair 0: d=1 + global merge + publish ------------------------------
  const float bos = tr[LSQ + ln];
  float R1[Ln];
#pragma unroll
  for (int lp = 0; lp < Ln; ++lp) R1[lp] = E[lp * Ln + ln];
  int w1c = 1;
  const int endd[8] = {8, 9, 10, 11, 12, 5, 6, 7};  // chain end per residue

  // seed t=0: alpha0 = exp(seg[b,0,0,:]+bos)  (reference stores exp'd value)
  {
    const float a0 = __expf(seg[SIDX(b, 0, 0) + ln] + bos);
    const float wm = wmaxred(act ? a0 : NEGINF);
    if ((tp & 63) == 0) redbuf[0][wv] = wm;
    __hip_atomic_store(&rfl[wv], 0, REL, WG);
    while (__hip_atomic_load(&rfl[wv ^ 1], ACQ, WG) < 0) {}
    const float C0 = fmaxf(redbuf[0][0], redbuf[0][1]);
    const float ax0 = __expf(a0 - C0);
    if (act) AlbR[0][tp] = ax0;
    if (tid == 0) CRng[0] = C0;
    __hip_atomic_store(&seqAw[wv], 0, REL, WG);
    if (act)
      __hip_atomic_store(&axp[((size_t)b * Tn + 0) * Ln + tp], pack2(ax0, C0),
                         RLX, AGENT);
  }

  for (int t = 1; t < Tn; ++t) {
    const int s = t - 1;
    // issue all independent loads for this step first
    u64 u[8];
#pragma unroll
    for (int jj = 0; jj < 8; ++jj)
      if (t >= endd[jj])
        u[jj] = __hip_atomic_load(
            &acc[(((size_t)jj * 4 + b) * Tn + t) * Ln + ln], RLX, AGENT);
    const float s1 = seg[SIDX(b, t, t) + ln];
    const float sz = (t <= Wn) ? seg[SIDX(b, 0, t) + ln] : 0.f;

    const int w1 = (t <= Wn) ? t : Wn;
    if (w1 > w1c) {
      w1c = w1;
#pragma unroll
      for (int lp = 0; lp < Ln; ++lp) R1[lp] *= E[lp * Ln + ln];
    }
    float i0 = 0, i1 = 0, i2 = 0, i3 = 0;
    const float4* A4 = (const float4*)AlbR[s & 7];
#pragma unroll
    for (int q = 0; q < 24; ++q) {
      float4 a = A4[q];
      i0 = fmaf(a.x, R1[4 * q + 0], i0);
      i1 = fmaf(a.y, R1[4 * q + 1], i1);
      i2 = fmaf(a.z, R1[4 * q + 2], i2);
      i3 = fmaf(a.w, R1[4 * q + 3], i3);
    }
    const float c1 =
        CRng[s & 7] + (float)w1 * s1 + __logf((i0 + i1) + (i2 + i3));

    // in-block contributions d=2,3,4
    float cc[3];
#pragma unroll
    for (int k = 1; k <= 3; ++k) {
      if (t >= k + 1) {
        while (__hip_atomic_load(&sp[k - 1][wv], ACQ, WG) < t) {}
        cc[k - 1] = slotC[t & 3][k - 1][ln];
      } else
        cc[k - 1] = NEGINF;
    }
    // external chain ends
    float em[8], ev[8];
#pragma unroll
    for (int jj = 0; jj < 8; ++jj) {
      if (t >= endd[jj]) {
        const size_t aIdx = (((size_t)jj * 4 + b) * Tn + t) * Ln + ln;
        while (((u[jj] >> 32) & 0xFFu) != (u32)endd[jj])
          u[jj] = __hip_atomic_load(&acc[aIdx], RLX, AGENT);
        em[jj] = __uint_as_float((u32)u[jj]);
        ev[jj] = __uint_as_float(((u32)(u[jj] >> 32)) & ~0xFFu);
      } else {
        em[jj] = NEGINF;
        ev[jj] = 0.f;
      }
    }
    const float zv = (t <= Wn) ? (float)(t + 1) * (sz + bos) : NEGINF;

    // single-max LSE merge of {c1, cc[0..2], (em,ev)[0..7], zv}
    float M = c1;
#pragma unroll
    for (int k = 0; k < 3; ++k) M = fmaxf(M, cc[k]);
#pragma unroll
    for (int jj = 0; jj < 8; ++jj) M = fmaxf(M, em[jj]);
    M = fmaxf(M, zv);
    float vs = __expf(c1 - M) + __expf(zv - M);
#pragma unroll
    for (int k = 0; k < 3; ++k) vs += __expf(cc[k] - M);
#pragma unroll
    for (int jj = 0; jj < 8; ++jj) vs += ev[jj] * __expf(em[jj] - M);
    const float alpha = M + __logf(vs);

    // block-wide C = max(alpha) over 96 (pair0's two waves only)
    const float wm = wmaxred(act ? alpha : NEGINF);
    if ((tp & 63) == 0) redbuf[t & 1][wv] = wm;
    __hip_atomic_store(&rfl[wv], t, REL, WG);
    while (__hip_atomic_load(&rfl[wv ^ 1], ACQ, WG) < t) {}
    const float C = fmaxf(redbuf[t & 1][0], redbuf[t & 1][1]);
    const float axn = __expf(alpha - C);
    if (act) AlbR[t & 7][tp] = axn;
    if (tid == 0) CRng[t & 7] = C;
    __hip_atomic_store(&seqAw[wv], t, REL, WG);
    if (act)
      __hip_atomic_store(&axp[((size_t)b * Tn + t) * Ln + tp], pack2(axn, C),
                         RLX, AGENT);

    if (t == Tn - 1) {
      const float sm = wsumred(act ? axn : 0.f);
      if ((tp & 63) == 0) redbuf[(t + 1) & 1][wv] = sm;
      __hip_atomic_store(&rfl[wv], t + 1, REL, WG);
      while (__hip_atomic_load(&rfl[wv ^ 1], ACQ, WG) < t + 1) {}
      if (tid == 0)
        out[b] = C + __logf(redbuf[(t + 1) & 1][0] + redbuf[(t + 1) & 1][1]);
    }
  }
}

extern "C" void kernel_launch(void* const* d_in, const int* in_sizes, int n_in,
                              void* d_out, int out_size, void* d_ws,
                              size_t ws_size, hipStream_t stream) {
  const float* seg = (const float*)d_in[0];  // (4,512,512,96) f32
  const float* tr = (const float*)d_in[1];   // (97,96) f32
  float* out = (float*)d_out;                // (4,) f32

  u64* axp = (u64*)d_ws;                     // [4][512][96]
  u64* acc = axp + (size_t)4 * Tn * Ln;      // [8][4][512][96]

  hipLaunchKernelGGL(init_ws, dim3(2048), dim3(256), 0, stream, (u64*)d_ws);
  hipLaunchKernelGGL(semicrf, dim3(4 * BPB), dim3(512), 0, stream, seg, tr,
                     out, axp, acc);
}